// Round 1
// baseline (384.063 us; speedup 1.0000x reference)
//
#include <hip/hip_runtime.h>
#include <cstddef>

#define A_ATOMS 96
#define BATCH   128
#define NNODES  12288   // B*A
#define NROWS3  36864   // N*3

__device__ __forceinline__ float silu_f(float x) {
    return x / (1.0f + __expf(-x));
}

// ---------------- generic GEMM: C = act(A@W + bias), N=128 fixed ------------
// BM rows/block, 256 threads, thread tile TM x 8, K-chunk 8.
template<int BM, int TM, int ACT>
__global__ __launch_bounds__(256)
void gemm128_k(const float* __restrict__ A, const float* __restrict__ W,
               const float* __restrict__ bias, float* __restrict__ C,
               int M, int K) {
    __shared__ float As[8][BM];    // transposed: As[k][m]
    __shared__ float Bs[8][128];
    const int t  = threadIdx.x;
    const int tx = t & 15;         // col group: cols tx*8..+7
    const int ty = t >> 4;         // row group: rows ty*TM..+TM-1
    const int row0 = blockIdx.x * BM;

    float acc[TM][8];
#pragma unroll
    for (int i = 0; i < TM; i++)
#pragma unroll
        for (int j = 0; j < 8; j++) acc[i][j] = 0.0f;

    for (int kc = 0; kc < K; kc += 8) {
        // stage A tile (BM x 8, transposed into As)
        if (BM == 128) {
            const int m  = t >> 1;
            const int k4 = (t & 1) * 4;
            float4 av = *(const float4*)(A + (size_t)(row0 + m) * K + kc + k4);
            As[k4 + 0][m] = av.x; As[k4 + 1][m] = av.y;
            As[k4 + 2][m] = av.z; As[k4 + 3][m] = av.w;
        } else { // BM == 64
            const int m  = t >> 2;
            const int k2 = (t & 3) * 2;
            float2 av = *(const float2*)(A + (size_t)(row0 + m) * K + kc + k2);
            As[k2 + 0][m] = av.x; As[k2 + 1][m] = av.y;
        }
        // stage B tile (8 x 128)
        {
            const int kb = t >> 5;
            const int n4 = (t & 31) * 4;
            *(float4*)&Bs[kb][n4] = *(const float4*)(W + (size_t)(kc + kb) * 128 + n4);
        }
        __syncthreads();
#pragma unroll
        for (int k = 0; k < 8; k++) {
            float bf[8], af[TM];
            *(float4*)&bf[0] = *(const float4*)&Bs[k][tx * 8];
            *(float4*)&bf[4] = *(const float4*)&Bs[k][tx * 8 + 4];
            *(float4*)&af[0] = *(const float4*)&As[k][ty * TM];
            if (TM == 8) *(float4*)&af[4] = *(const float4*)&As[k][ty * TM + 4];
#pragma unroll
            for (int i = 0; i < TM; i++)
#pragma unroll
                for (int j = 0; j < 8; j++) acc[i][j] += af[i] * bf[j];
        }
        __syncthreads();
    }
    // epilogue
#pragma unroll
    for (int i = 0; i < TM; i++) {
        const int row = row0 + ty * TM + i;
        float v[8];
#pragma unroll
        for (int j = 0; j < 8; j++) {
            float x = acc[i][j];
            if (bias) x += bias[tx * 8 + j];
            if (ACT == 1) x = silu_f(x);
            v[j] = x;
        }
        float* cp = C + (size_t)row * 128 + tx * 8;
        *(float4*)cp       = *(float4*)&v[0];
        *(float4*)(cp + 4) = *(float4*)&v[4];
    }
}

// ---------------- glue1: xin[n] = [scalar_rep[n] (128), ||vV||_d (64)] ------
__global__ __launch_bounds__(256)
void glue1_k(const float* __restrict__ srep, const float* __restrict__ vmix,
             float* __restrict__ xin) {
    const int t = threadIdx.x;
    const int n = blockIdx.x * 4 + (t >> 6);
    const int lane = t & 63;
    const size_t sb = (size_t)n * 128;
    const size_t xb = (size_t)n * 192;
    xin[xb + lane]      = srep[sb + lane];
    xin[xb + 64 + lane] = srep[sb + 64 + lane];
    float v0 = vmix[((size_t)(3 * n + 0)) * 128 + lane];
    float v1 = vmix[((size_t)(3 * n + 1)) * 128 + lane];
    float v2 = vmix[((size_t)(3 * n + 2)) * 128 + lane];
    xin[xb + 128 + lane] = sqrtf(v0 * v0 + v1 * v1 + v2 * v2);
}

// ---------------- glue2: per-node block-1 epilogue + full block-2 -----------
#define RED64(v) { v += __shfl_xor(v, 1); v += __shfl_xor(v, 2); v += __shfl_xor(v, 4); \
                   v += __shfl_xor(v, 8); v += __shfl_xor(v, 16); v += __shfl_xor(v, 32); }

__global__ __launch_bounds__(256)
void glue2_k(const float* __restrict__ x1, const float* __restrict__ vmix,
             const float* __restrict__ mixW2,
             const float* __restrict__ W1, const float* __restrict__ b1,
             const float* __restrict__ W2, const float* __restrict__ b2,
             float* __restrict__ l0v, float* __restrict__ l1v) {
    __shared__ float s1s[4][64];
    const int t = threadIdx.x;
    const int w = t >> 6, lane = t & 63;
    const int n = blockIdx.x * 4 + w;

    const float xa = x1[(size_t)n * 128 + lane];        // pre-silu s_out
    const float xb = x1[(size_t)n * 128 + 64 + lane];   // gate
    const float s1 = silu_f(xa);
    const float v1_0 = xb * vmix[((size_t)(3 * n + 0)) * 128 + 64 + lane];
    const float v1_1 = xb * vmix[((size_t)(3 * n + 1)) * 128 + 64 + lane];
    const float v1_2 = xb * vmix[((size_t)(3 * n + 2)) * 128 + 64 + lane];

    const float w0 = mixW2[lane * 2 + 0], w1 = mixW2[lane * 2 + 1];
    float p0 = v1_0 * w0, p1 = v1_0 * w1;
    float p2 = v1_1 * w0, p3 = v1_1 * w1;
    float p4 = v1_2 * w0, p5 = v1_2 * w1;
    RED64(p0); RED64(p1); RED64(p2); RED64(p3); RED64(p4); RED64(p5);
    // p0,p2,p4 = vV2 (col 0);  p1,p3,p5 = vW2 (col 1)
    const float vn2 = sqrtf(p0 * p0 + p2 * p2 + p4 * p4);

    s1s[w][lane] = s1;
    __syncthreads();

    float acc = b1[lane] + vn2 * W1[64 * 64 + lane];
    for (int i2 = 0; i2 < 64; i2++) acc += s1s[w][i2] * W1[i2 * 64 + lane];
    const float h2 = silu_f(acc);

    float q0 = h2 * W2[lane * 2 + 0];
    float q1 = h2 * W2[lane * 2 + 1];
    RED64(q0); RED64(q1);

    if (lane == 0) {
        const float s_out = q0 + b2[0];   // sact=False: no silu
        const float gate  = q1 + b2[1];
        l0v[n] = s_out;
        l1v[(size_t)n * 3 + 0] = gate * p1;
        l1v[(size_t)n * 3 + 1] = gate * p3;
        l1v[(size_t)n * 3 + 2] = gate * p5;
    }
}

// ---------------- pair kernel: all four small MLPs + scattered write --------
__global__ __launch_bounds__(192)
void pair_k(const float* __restrict__ l0v, const float* __restrict__ l1v,
            const float* __restrict__ pos,
            const float* __restrict__ vvW1, const float* __restrict__ vvb1,
            const float* __restrict__ vvW2, const float* __restrict__ vvb2,
            const float* __restrict__ vrW1, const float* __restrict__ vrb1,
            const float* __restrict__ vrW2, const float* __restrict__ vrb2,
            const float* __restrict__ sW1,  const float* __restrict__ sb1,
            const float* __restrict__ sW2,  const float* __restrict__ sb2,
            const float* __restrict__ hW1,  const float* __restrict__ hb1,
            const float* __restrict__ hW2,  const float* __restrict__ hb2,
            float* __restrict__ out) {
    const int t = threadIdx.x;
    const int b = blockIdx.y;
    const int i = blockIdx.x * 2 + t / 96;
    const int j = t % 96;
    const int ni = b * A_ATOMS + i;
    const int nj = b * A_ATOMS + j;

    const float li0 = l1v[ni * 3 + 0], li1 = l1v[ni * 3 + 1], li2 = l1v[ni * 3 + 2];
    const float lj0 = l1v[nj * 3 + 0], lj1 = l1v[nj * 3 + 1], lj2 = l1v[nj * 3 + 2];
    const float pj0 = pos[nj * 3 + 0], pj1 = pos[nj * 3 + 1], pj2 = pos[nj * 3 + 2];
    const float s0i = l0v[ni], s0j = l0v[nj];

    float vin[9] = { li0*lj0, li0*lj1, li0*lj2,
                     li1*lj0, li1*lj1, li1*lj2,
                     li2*lj0, li2*lj1, li2*lj2 };
    float rin[9] = { li0*pj0, li0*pj1, li0*pj2,
                     li1*pj0, li1*pj1, li1*pj2,
                     li2*pj0, li2*pj1, li2*pj2 };

    float t9[9];
#pragma unroll
    for (int l = 0; l < 9; l++) t9[l] = vvb2[l] + vrb2[l] + sb2[l];

    for (int h = 0; h < 30; h++) {
        float av = vvb1[h], ar = vrb1[h];
#pragma unroll
        for (int m = 0; m < 9; m++) {
            av += vin[m] * vvW1[m * 30 + h];
            ar += rin[m] * vrW1[m * 30 + h];
        }
        float as = sb1[h] + s0i * sW1[h] + s0j * sW1[30 + h];
        av = silu_f(av); ar = silu_f(ar); as = silu_f(as);
#pragma unroll
        for (int l = 0; l < 9; l++)
            t9[l] += av * vvW2[h * 9 + l] + ar * vrW2[h * 9 + l] + as * sW2[h * 9 + l];
    }

    float o9[9];
#pragma unroll
    for (int l = 0; l < 9; l++) o9[l] = hb2[l];
    for (int h = 0; h < 30; h++) {
        float a = hb1[h];
#pragma unroll
        for (int m = 0; m < 9; m++) a += t9[m] * hW1[m * 30 + h];
        a = silu_f(a);
#pragma unroll
        for (int l = 0; l < 9; l++) o9[l] += a * hW2[h * 9 + l];
    }

    // out[((b*A+i)*3+k)*288 + j*3 + l] = o9[3k+l]
    const size_t rb = (size_t)(b * A_ATOMS + i);
#pragma unroll
    for (int k = 0; k < 3; k++) {
        const size_t off = (rb * 3 + k) * 288 + (size_t)j * 3;
        out[off + 0] = o9[3 * k + 0];
        out[off + 1] = o9[3 * k + 1];
        out[off + 2] = o9[3 * k + 2];
    }
}

extern "C" void kernel_launch(void* const* d_in, const int* in_sizes, int n_in,
                              void* d_out, int out_size, void* d_ws, size_t ws_size,
                              hipStream_t stream) {
    const float* pos   = (const float*)d_in[0];
    const float* srep  = (const float*)d_in[1];
    const float* vrep  = (const float*)d_in[2];
    const float* mixW1 = (const float*)d_in[3];
    const float* sc1W1 = (const float*)d_in[4];
    const float* sc1b1 = (const float*)d_in[5];
    const float* sc1W2 = (const float*)d_in[6];
    const float* sc1b2 = (const float*)d_in[7];
    const float* mixW2 = (const float*)d_in[8];
    const float* sc2W1 = (const float*)d_in[9];
    const float* sc2b1 = (const float*)d_in[10];
    const float* sc2W2 = (const float*)d_in[11];
    const float* sc2b2 = (const float*)d_in[12];
    const float* vvW1  = (const float*)d_in[13];
    const float* vvb1  = (const float*)d_in[14];
    const float* vvW2  = (const float*)d_in[15];
    const float* vvb2  = (const float*)d_in[16];
    const float* vrW1  = (const float*)d_in[17];
    const float* vrb1  = (const float*)d_in[18];
    const float* vrW2  = (const float*)d_in[19];
    const float* vrb2  = (const float*)d_in[20];
    const float* sW1   = (const float*)d_in[21];
    const float* sb1   = (const float*)d_in[22];
    const float* sW2   = (const float*)d_in[23];
    const float* sb2   = (const float*)d_in[24];
    const float* hW1   = (const float*)d_in[25];
    const float* hb1   = (const float*)d_in[26];
    const float* hW2   = (const float*)d_in[27];
    const float* hb2   = (const float*)d_in[28];

    float* ws   = (float*)d_ws;
    float* vmix = ws;                       // 36864*128 = 4,718,592
    float* xin  = vmix + 4718592;           // 12288*192 = 2,359,296
    float* hmid = xin  + 2359296;           // 12288*128 = 1,572,864
    float* x1   = hmid + 1572864;           // 12288*128 = 1,572,864
    float* l0v  = x1   + 1572864;           // 12288
    float* l1v  = l0v  + 12288;             // 36864
    float* outf = (float*)d_out;

    // 1. vmix = vector_rep(36864x128) @ mix_W1(128x128)
    gemm128_k<128, 8, 0><<<288, 256, 0, stream>>>(vrep, mixW1, nullptr, vmix, NROWS3, 128);
    // 2. xin = [scalar_rep, ||vV||]
    glue1_k<<<NNODES / 4, 256, 0, stream>>>(srep, vmix, xin);
    // 3. hmid = silu(xin @ sc1_W1 + b1)
    gemm128_k<64, 4, 1><<<192, 256, 0, stream>>>(xin, sc1W1, sc1b1, hmid, NNODES, 192);
    // 4. x1 = hmid @ sc1_W2 + b2
    gemm128_k<64, 4, 0><<<192, 256, 0, stream>>>(hmid, sc1W2, sc1b2, x1, NNODES, 128);
    // 5. per-node epilogue + block 2 -> l0, l1
    glue2_k<<<NNODES / 4, 256, 0, stream>>>(x1, vmix, mixW2, sc2W1, sc2b1, sc2W2, sc2b2,
                                            l0v, l1v);
    // 6. pair stage
    pair_k<<<dim3(A_ATOMS / 2, BATCH), 192, 0, stream>>>(
        l0v, l1v, pos,
        vvW1, vvb1, vvW2, vvb2,
        vrW1, vrb1, vrW2, vrb2,
        sW1, sb1, sW2, sb2,
        hW1, hb1, hW2, hb2,
        outf);
}